// Round 1
// baseline (1721.443 us; speedup 1.0000x reference)
//
#include <hip/hip_runtime.h>
#include <hip/hip_bf16.h>
#include <stdint.h>

// Problem constants: B=32, LQ=T=D=1024, h=512. T+1=1025 padded to TP=1152.
#define DEVFN __device__ __forceinline__

typedef uint32_t v4u  __attribute__((ext_vector_type(4)));
typedef __bf16   v8bf __attribute__((ext_vector_type(8)));
typedef float    v4f  __attribute__((ext_vector_type(4)));

DEVFN unsigned short f2bf(float f) {
  unsigned u = __builtin_bit_cast(unsigned, f);
  unsigned r = (u + 0x7fffu + ((u >> 16) & 1u)) >> 16;   // RNE
  return (unsigned short)r;
}
DEVFN float bf2f(unsigned short s) {
  return __builtin_bit_cast(float, (unsigned)s << 16);
}

// ---------------- workspace layout (bytes, all 256-aligned) ----------------
constexpr size_t OFF_QK   = 0;                       // q|k bf16, 65536x1024   (q half also = residual for final GEMM)
constexpr size_t OFF_WQK  = OFF_QK  + 134217728ULL;
constexpr size_t OFF_W1   = OFF_WQK + 2097152ULL;
constexpr size_t OFF_W2   = OFF_W1  + 1048576ULL;
constexpr size_t OFF_W3   = OFF_W2  + 1048576ULL;
constexpr size_t OFF_DUM  = OFF_W3  + 4194304ULL;
constexpr size_t OFF_GIDX = OFF_DUM + 4096ULL;
constexpr size_t OFF_QP   = OFF_GIDX + 8192ULL;      // qp bf16 32768x1024 ; later reused as o12
constexpr size_t OFF_KP   = OFF_QP  + 67108864ULL;   // kp bf16 32768x1024 ; later reused as out
constexpr size_t OFF_KF   = OFF_KP  + 67108864ULL;   // kf bf16 32x1152x1024 ; later reused as attn (32768x1152)
constexpr size_t OFF_SC   = OFF_KF  + 75497472ULL;   // scores f32 32768x1152 ; later reused as a1|a2
constexpr size_t OFF_VFT  = OFF_SC  + 150994944ULL;  // vf^T bf16 32x1024x1152
constexpr size_t OFF_TFT  = OFF_VFT + 75497472ULL;   // tf^T bf16 32x1024x1152
// total = 654,323,712 bytes

// ---------------- scan: gidx[t] = mask[t] ? pos[t] : -1 ----------------
__global__ void scan_kernel(const int* __restrict__ supp, int* __restrict__ gidx) {
  __shared__ int s[1024];
  int t = threadIdx.x;
  int m = (supp[t] != 100) ? 1 : 0;
  s[t] = m;
  __syncthreads();
  for (int off = 1; off < 1024; off <<= 1) {
    int add = (t >= off) ? s[t - off] : 0;
    __syncthreads();
    s[t] += add;
    __syncthreads();
  }
  int pos = s[t] - 1;
  if (pos < 0) pos = 0;
  gidx[t] = m ? pos : -1;
}

// ---------------- f32 -> bf16 cast (x4 vectorized) ----------------
__global__ void cast_kernel(const float* __restrict__ in, unsigned short* __restrict__ out, int n4) {
  int i = blockIdx.x * blockDim.x + threadIdx.x;
  int stride = gridDim.x * blockDim.x;
  for (; i < n4; i += stride) {
    float4 v = reinterpret_cast<const float4*>(in)[i];
    ushort4 o;
    o.x = f2bf(v.x); o.y = f2bf(v.y); o.z = f2bf(v.z); o.w = f2bf(v.w);
    reinterpret_cast<ushort4*>(out)[i] = o;
  }
}

// ---------------- kf gather: kf[b][t][:] = kp[b][gidx[t]] | dummy | 0 ----------------
__global__ void gather_kf_kernel(const unsigned short* __restrict__ kp,
                                 const unsigned short* __restrict__ dummyb,
                                 const int* __restrict__ gidx,
                                 unsigned short* __restrict__ kf) {
  int t = blockIdx.x;           // 0..1151
  int b = blockIdx.y;           // 0..31
  uint2* dst = reinterpret_cast<uint2*>(kf + ((size_t)b * 1152 + t) * 1024);
  if (t >= 1025) { dst[threadIdx.x] = make_uint2(0u, 0u); return; }
  const unsigned short* src;
  if (t == 1024) src = dummyb;
  else {
    int g = gidx[t];
    src = (g >= 0) ? kp + ((size_t)b * 1024 + g) * 1024 : dummyb;
  }
  dst[threadIdx.x] = reinterpret_cast<const uint2*>(src)[threadIdx.x];
}

// ---------------- transpose+gather: vft[b][d][t], tft[b][d][t] ----------------
__global__ void transpose_gather_kernel(const float* __restrict__ v, const float* __restrict__ tsp,
                                        const int* __restrict__ gidx,
                                        unsigned short* __restrict__ vft, unsigned short* __restrict__ tft) {
  __shared__ float tv[32][33];
  __shared__ float tt[32][33];
  int b = blockIdx.z;
  int d0 = blockIdx.x * 32, t0 = blockIdx.y * 32;
  int tx = threadIdx.x, ty = threadIdx.y;  // (32, 8)
  #pragma unroll
  for (int r = 0; r < 4; ++r) {
    int lt = ty + r * 8;
    int t = t0 + lt;
    float vv = 0.f, tvv = 0.f;
    if (t < 1024) {
      int g = gidx[t];
      if (g >= 0) vv = v[((size_t)b * 1024 + g) * 1024 + d0 + tx];
      tvv = tsp[((size_t)b * 1024 + t) * 1024 + d0 + tx];
    }
    tv[lt][tx] = vv;
    tt[lt][tx] = tvv;
  }
  __syncthreads();
  #pragma unroll
  for (int r = 0; r < 4; ++r) {
    int ld = ty + r * 8;
    size_t o = ((size_t)b * 1024 + d0 + ld) * 1152 + t0 + tx;
    vft[o] = f2bf(tv[tx][ld]);
    tft[o] = f2bf(tt[tx][ld]);
  }
}

// ---------------- softmax over 1025 cols, write bf16 attn (1152 w/ zero pad) ----------------
__global__ __launch_bounds__(256) void softmax_kernel(const float* __restrict__ S, unsigned short* __restrict__ P) {
  __shared__ float redm[4];
  __shared__ float reds[4];
  const size_t row = blockIdx.x;
  const float* s = S + row * 1152;
  unsigned short* p = P + row * 1152;
  const int tid = threadIdx.x;
  float vals[5], ev[5];
  float m = -1e30f;
  #pragma unroll
  for (int j = 0; j < 5; ++j) {
    int idx = tid + j * 256;
    if (idx < 1025) { vals[j] = s[idx]; m = fmaxf(m, vals[j]); }
  }
  #pragma unroll
  for (int off = 32; off > 0; off >>= 1) m = fmaxf(m, __shfl_down(m, off, 64));
  if ((tid & 63) == 0) redm[tid >> 6] = m;
  __syncthreads();
  m = fmaxf(fmaxf(redm[0], redm[1]), fmaxf(redm[2], redm[3]));
  float sum = 0.f;
  #pragma unroll
  for (int j = 0; j < 5; ++j) {
    int idx = tid + j * 256;
    if (idx < 1025) { ev[j] = __expf(vals[j] - m); sum += ev[j]; }
  }
  #pragma unroll
  for (int off = 32; off > 0; off >>= 1) sum += __shfl_down(sum, off, 64);
  if ((tid & 63) == 0) reds[tid >> 6] = sum;
  __syncthreads();
  sum = reds[0] + reds[1] + reds[2] + reds[3];
  float inv = 1.f / sum;
  #pragma unroll
  for (int j = 0; j < 5; ++j) {
    int idx = tid + j * 256;
    if (idx < 1025) p[idx] = f2bf(ev[j] * inv);
  }
  int iz = 1025 + tid;
  if (iz < 1152) p[iz] = 0;
}

// ---------------- a1 = bf16(out*q), a2 = bf16(q-out) ----------------
__global__ void a12_kernel(const unsigned short* __restrict__ outb, const float* __restrict__ q,
                           unsigned short* __restrict__ a1, unsigned short* __restrict__ a2, int n4) {
  int i = blockIdx.x * blockDim.x + threadIdx.x;
  int stride = gridDim.x * blockDim.x;
  for (; i < n4; i += stride) {
    ushort4 ov = reinterpret_cast<const ushort4*>(outb)[i];
    float4 qv = reinterpret_cast<const float4*>(q)[i];
    float o0 = bf2f(ov.x), o1 = bf2f(ov.y), o2 = bf2f(ov.z), o3 = bf2f(ov.w);
    ushort4 r1, r2;
    r1.x = f2bf(o0 * qv.x); r1.y = f2bf(o1 * qv.y); r1.z = f2bf(o2 * qv.z); r1.w = f2bf(o3 * qv.w);
    r2.x = f2bf(qv.x - o0); r2.y = f2bf(qv.y - o1); r2.z = f2bf(qv.z - o2); r2.w = f2bf(qv.w - o3);
    reinterpret_cast<ushort4*>(a1)[i] = r1;
    reinterpret_cast<ushort4*>(a2)[i] = r2;
  }
}

// ---------------- NT GEMM: C[M,N] = epi( A[M,K] @ B[N,K]^T ) ----------------
// 128x128 tile, BK=64, 4 waves, 4x4 MFMA 16x16x32 bf16 each.
// A2/splitK0: rows of A come from A for k<splitK0, from A2 (k-splitK0) otherwise.
// EPI: 0 = bf16 store, 1 = f32 store * scale, 2 = bf16 relu(x+bias), 3 = f32 x+bias.
template<int EPI>
__global__ __launch_bounds__(256) void gemm_nt(
    const unsigned short* __restrict__ A, const unsigned short* __restrict__ A2, int splitK0,
    const unsigned short* __restrict__ Bm, void* __restrict__ C,
    const float* __restrict__ bias, float scale,
    int K, int lda, int ldb, int ldc,
    long long sAb, long long sBb, long long sCb) {
  __shared__ alignas(16) unsigned short As[128][72];
  __shared__ alignas(16) unsigned short Bs[128][72];
  const int tid = threadIdx.x;
  const int bmb = blockIdx.x * 128;
  const int bnb = blockIdx.y * 128;
  const unsigned short* Abase = A + (long long)blockIdx.z * sAb;
  const unsigned short* Bbase = Bm + (long long)blockIdx.z * sBb;

  const int wave = tid >> 6;
  const int lane = tid & 63;
  const int quad = lane >> 4;
  const int r    = lane & 15;
  const int wm = (wave >> 1) * 64;
  const int wn = (wave & 1) * 64;

  v4f acc[4][4];
  #pragma unroll
  for (int i = 0; i < 4; ++i)
    #pragma unroll
    for (int j = 0; j < 4; ++j)
      acc[i][j] = (v4f){0.f, 0.f, 0.f, 0.f};

  for (int k0 = 0; k0 < K; k0 += 64) {
    const unsigned short* Asrc;
    int ka;
    if (k0 < splitK0) { Asrc = Abase; ka = k0; }
    else              { Asrc = A2;   ka = k0 - splitK0; }
    #pragma unroll
    for (int c = 0; c < 4; ++c) {
      int idx = tid + c * 256;           // 0..1023  (128 rows x 8 chunks of 8 bf16)
      int row = idx >> 3;
      int kc  = (idx & 7) << 3;
      v4u va = *reinterpret_cast<const v4u*>(Asrc + (long long)(bmb + row) * lda + ka + kc);
      *reinterpret_cast<v4u*>(&As[row][kc]) = va;
      v4u vb = *reinterpret_cast<const v4u*>(Bbase + (long long)(bnb + row) * ldb + k0 + kc);
      *reinterpret_cast<v4u*>(&Bs[row][kc]) = vb;
    }
    __syncthreads();
    #pragma unroll
    for (int kk = 0; kk < 64; kk += 32) {
      v8bf af[4], bfv[4];
      #pragma unroll
      for (int t = 0; t < 4; ++t) {
        af[t]  = __builtin_bit_cast(v8bf, *reinterpret_cast<const v4u*>(&As[wm + t * 16 + r][kk + quad * 8]));
        bfv[t] = __builtin_bit_cast(v8bf, *reinterpret_cast<const v4u*>(&Bs[wn + t * 16 + r][kk + quad * 8]));
      }
      #pragma unroll
      for (int mt = 0; mt < 4; ++mt)
        #pragma unroll
        for (int nt = 0; nt < 4; ++nt)
          acc[mt][nt] = __builtin_amdgcn_mfma_f32_16x16x32_bf16(af[mt], bfv[nt], acc[mt][nt], 0, 0, 0);
    }
    __syncthreads();
  }

  long long cb = (long long)blockIdx.z * sCb;
  #pragma unroll
  for (int mt = 0; mt < 4; ++mt) {
    #pragma unroll
    for (int nt = 0; nt < 4; ++nt) {
      int col  = bnb + wn + nt * 16 + r;
      int row0 = bmb + wm + mt * 16 + quad * 4;
      #pragma unroll
      for (int i = 0; i < 4; ++i) {
        float val = acc[mt][nt][i];
        long long off = cb + (long long)(row0 + i) * ldc + col;
        if constexpr (EPI == 0) {
          ((unsigned short*)C)[off] = f2bf(val);
        } else if constexpr (EPI == 1) {
          ((float*)C)[off] = val * scale;
        } else if constexpr (EPI == 2) {
          val = fmaxf(val + bias[col], 0.f);
          ((unsigned short*)C)[off] = f2bf(val);
        } else {
          ((float*)C)[off] = val + bias[col];
        }
      }
    }
  }
}

// ---------------- host ----------------
extern "C" void kernel_launch(void* const* d_in, const int* in_sizes, int n_in,
                              void* d_out, int out_size, void* d_ws, size_t ws_size,
                              hipStream_t stream) {
  const float* q    = (const float*)d_in[0];
  const float* k    = (const float*)d_in[1];
  const float* v    = (const float*)d_in[2];
  const float* tsp  = (const float*)d_in[3];
  const int*   supp = (const int*)d_in[4];
  const float* wqk  = (const float*)d_in[5];
  const float* dum  = (const float*)d_in[6];
  const float* w1   = (const float*)d_in[7];
  const float* b1   = (const float*)d_in[8];
  const float* w2   = (const float*)d_in[9];
  const float* b2   = (const float*)d_in[10];
  const float* w3   = (const float*)d_in[11];
  const float* b3   = (const float*)d_in[12];

  char* ws = (char*)d_ws;
  unsigned short* qkb   = (unsigned short*)(ws + OFF_QK);    // q bf16 (first half) = residual
  unsigned short* kb    = qkb + 33554432;
  unsigned short* wqkb  = (unsigned short*)(ws + OFF_WQK);
  unsigned short* w1b   = (unsigned short*)(ws + OFF_W1);
  unsigned short* w2b   = (unsigned short*)(ws + OFF_W2);
  unsigned short* w3b   = (unsigned short*)(ws + OFF_W3);
  unsigned short* dumb  = (unsigned short*)(ws + OFF_DUM);
  int*            gidx  = (int*)(ws + OFF_GIDX);
  unsigned short* qpb   = (unsigned short*)(ws + OFF_QP);    // 65536x1024 C of proj GEMM (qp then kp)
  unsigned short* kpb   = (unsigned short*)(ws + OFF_KP);
  unsigned short* kfb   = (unsigned short*)(ws + OFF_KF);
  float*          scor  = (float*)(ws + OFF_SC);
  unsigned short* vftb  = (unsigned short*)(ws + OFF_VFT);
  unsigned short* tftb  = (unsigned short*)(ws + OFF_TFT);
  // time-aliased:
  unsigned short* attnb = kfb;                                // after kf dead
  unsigned short* outb  = kpb;                                // after kp dead
  unsigned short* a1b   = (unsigned short*)(ws + OFF_SC);     // after scores dead
  unsigned short* a2b   = a1b + 33554432;
  unsigned short* o12b  = qpb;                                // after qp dead

  const int BIGK = 1 << 30;

  // 1. scan
  scan_kernel<<<1, 1024, 0, stream>>>(supp, gidx);
  // 2. casts
  cast_kernel<<<4096, 256, 0, stream>>>(q, qkb, 8388608);
  cast_kernel<<<4096, 256, 0, stream>>>(k, kb, 8388608);
  cast_kernel<<<1024, 256, 0, stream>>>(wqk, wqkb, 262144);
  cast_kernel<<<512, 256, 0, stream>>>(w1, w1b, 131072);
  cast_kernel<<<512, 256, 0, stream>>>(w2, w2b, 131072);
  cast_kernel<<<1024, 256, 0, stream>>>(w3, w3b, 524288);
  cast_kernel<<<1, 256, 0, stream>>>(dum, dumb, 256);
  // 3. [qp;kp] = [q;k] @ wqk^T
  gemm_nt<0><<<dim3(512, 8, 1), 256, 0, stream>>>(qkb, qkb, BIGK, wqkb, qpb, nullptr, 1.f,
                                                  1024, 1024, 1024, 1024, 0, 0, 0);
  // 4. kf gather
  gather_kf_kernel<<<dim3(1152, 32), 256, 0, stream>>>(kpb, dumb, gidx, kfb);
  // 5. scores = qp @ kf^T / 32   (batched)
  gemm_nt<1><<<dim3(8, 9, 32), 256, 0, stream>>>(qpb, qpb, BIGK, kfb, scor, nullptr, 0.03125f,
                                                 1024, 1024, 1024, 1152, 1048576LL, 1179648LL, 1179648LL);
  // 6. softmax -> attn bf16
  softmax_kernel<<<32768, 256, 0, stream>>>(scor, attnb);
  // 7. vf^T, tf^T
  transpose_gather_kernel<<<dim3(32, 36, 32), dim3(32, 8), 0, stream>>>(v, tsp, gidx, vftb, tftb);
  // 8. out = attn @ vf   (bf16)
  gemm_nt<0><<<dim3(8, 8, 32), 256, 0, stream>>>(attnb, attnb, BIGK, vftb, outb, nullptr, 1.f,
                                                 1152, 1152, 1152, 1024, 1179648LL, 1179648LL, 1048576LL);
  // 9. tsp_out = attn @ tf  (fp32, straight to d_out 2nd half)
  gemm_nt<1><<<dim3(8, 8, 32), 256, 0, stream>>>(attnb, attnb, BIGK, tftb, (float*)d_out + 33554432, nullptr, 1.f,
                                                 1152, 1152, 1152, 1024, 1179648LL, 1179648LL, 1048576LL);
  // 10. a1 = out*q, a2 = q-out
  a12_kernel<<<4096, 256, 0, stream>>>(outb, q, a1b, a2b, 8388608);
  // 11. o1 = relu(a1@w1^T + b1) -> o12[:, 0:512] ; o2 likewise -> o12[:, 512:1024]
  gemm_nt<2><<<dim3(256, 4, 1), 256, 0, stream>>>(a1b, a1b, BIGK, w1b, o12b, b1, 1.f,
                                                  1024, 1024, 1024, 1024, 0, 0, 0);
  gemm_nt<2><<<dim3(256, 4, 1), 256, 0, stream>>>(a2b, a2b, BIGK, w2b, o12b + 512, b2, 1.f,
                                                  1024, 1024, 1024, 1024, 0, 0, 0);
  // 12. output = [o12 | q] @ w3^T + b3  (split-K A pointers, fp32 to d_out 1st half)
  gemm_nt<3><<<dim3(256, 8, 1), 256, 0, stream>>>(o12b, qkb, 1024, w3b, d_out, b3, 1.f,
                                                  2048, 1024, 2048, 1024, 0, 0, 0);
}